// Round 1
// baseline (505.162 us; speedup 1.0000x reference)
//
#include <hip/hip_runtime.h>
#include <hip/hip_bf16.h>
#include <math.h>

#define TT 2000
#define NN 256
#define DD 256
#define SS 45
#define SOUT 48
#define NTRANS_C 40
#define CHUNKS 40
#define CLEN 50   // TT / CHUNKS
#define WST 260   // LDS row stride (floats) for W tile

// ---------------- Kernel A: GEMM + activations ----------------
// grid 2000 x 256 threads; block covers 256 rows; thread = 8 rows x 6 s-cols.
__global__ __launch_bounds__(256) void kA_gemm(const float* __restrict__ x,
                                               const float* __restrict__ W,
                                               const float* __restrict__ b,
                                               float* __restrict__ out) {
    __shared__ float Wl[48 * WST];
    const int tid = threadIdx.x;
    // stage W (45x256 f32) into LDS
    for (int idx = tid; idx < (SS * DD) / 4; idx += 256) {
        const float4 v = reinterpret_cast<const float4*>(W)[idx];
        const int f = idx * 4;
        const int s = f >> 8;
        const int d = f & 255;
        float* p = &Wl[s * WST + d];
        p[0] = v.x; p[1] = v.y; p[2] = v.z; p[3] = v.w;
    }
    __syncthreads();

    const int sgrp = tid & 7;
    const int rgrp = tid >> 3;
    const long row0 = (long)blockIdx.x * 256 + (long)rgrp * 8;
    const float* xr = x + row0 * DD;
    const int s0 = sgrp * 6;

    float acc[8][6];
#pragma unroll
    for (int r = 0; r < 8; ++r)
#pragma unroll
        for (int q = 0; q < 6; ++q) acc[r][q] = 0.f;

    for (int d = 0; d < DD; d += 4) {
        float4 w4[6];
#pragma unroll
        for (int q = 0; q < 6; ++q)
            w4[q] = *reinterpret_cast<const float4*>(&Wl[(s0 + q) * WST + d]);
#pragma unroll
        for (int r = 0; r < 8; ++r) {
            const float4 x4 = *reinterpret_cast<const float4*>(&xr[(long)r * DD + d]);
#pragma unroll
            for (int q = 0; q < 6; ++q)
                acc[r][q] += x4.x * w4[q].x + x4.y * w4[q].y +
                             x4.z * w4[q].z + x4.w * w4[q].w;
        }
    }
    // epilogue: s<40 -> 5*tanh(y); 40<=s<45 -> raw y; s>=45 skipped
#pragma unroll
    for (int r = 0; r < 8; ++r) {
        float* orow = out + (row0 + r) * SOUT;
#pragma unroll
        for (int q = 0; q < 6; ++q) {
            const int s = s0 + q;
            if (s < SS) {
                const float y = acc[r][q] + b[s];
                orow[s] = (s < NTRANS_C) ? 5.f * tanhf(y) : y;
            }
        }
    }
}

// ---------------- butterfly logsumexp helpers ----------------
__device__ inline float lse8(float v) {
    float m = v;
    m = fmaxf(m, __shfl_xor(m, 1));
    m = fmaxf(m, __shfl_xor(m, 2));
    m = fmaxf(m, __shfl_xor(m, 4));
    float e = __expf(v - m);
    e += __shfl_xor(e, 1);
    e += __shfl_xor(e, 2);
    e += __shfl_xor(e, 4);
    return m + __logf(e);
}

__device__ inline float lse64(float v) {
    float m = v;
#pragma unroll
    for (int d = 1; d < 64; d <<= 1) m = fmaxf(m, __shfl_xor(m, d));
    float e = __expf(v - m);
#pragma unroll
    for (int d = 1; d < 64; d <<= 1) e += __shfl_xor(e, d);
    return m + __logf(e);
}

// ---------------- Kernel B: per-(n,chunk) 8x8 log transfer matrix ----------
// one wave64: lane = col*8 + j holds M[j][col]
__global__ __launch_bounds__(64) void kB_scan(const float* __restrict__ out,
                                              float* __restrict__ gbuf) {
    const int n = blockIdx.x;
    const int c = blockIdx.y;
    const int l = threadIdx.x;
    const int col = l >> 3;
    const int j = l & 7;
    const int k = j & 3;
    float m = (j == col) ? 0.f : -1e30f;
    const int t0 = c * CLEN;
    for (int t = t0; t < t0 + CLEN; ++t) {
        const float* s = out + ((long)t * NN + n) * SOUT;
        const float s0 = s[j], s1 = s[8 + j], s2 = s[16 + j], s3 = s[24 + j];
        const float sa = s[32 + k], sb = s[36 + k];
        const float r0 = lse8(m + s0);
        const float r1 = lse8(m + s1);
        const float r2 = lse8(m + s2);
        const float r3 = lse8(m + s3);
        // base2 rows: new[4+k] = logaddexp(M[k]+s[32+k], M[k+4]+s[36+k])
        const float mk  = __shfl(m, (l & ~7) | k);
        const float mk4 = __shfl(m, (l & ~7) | (k + 4));
        const float pa = mk + sa, pb = mk4 + sb;
        const float mx = fmaxf(pa, pb);
        const float rb = mx + __logf(__expf(pa - mx) + __expf(pb - mx));
        const float rlow = (j < 2) ? ((j == 0) ? r0 : r1)
                                   : ((j == 2) ? r2 : r3);
        m = (j < 4) ? rlow : rb;
    }
    // store G[j][col] at flat pos col*8+j = l
    gbuf[((long)(n * CHUNKS + c)) * 64 + l] = m;
}

// ---------------- Kernel C: fold chunk matrices, emit logZ/T -------------
__global__ __launch_bounds__(64) void kC_combine(const float* __restrict__ gbuf,
                                                 float* __restrict__ logZT) {
    const int n = blockIdx.x;
    const int l = threadIdx.x;
    float u = -logf(8.f);  // u[col], col = l&7 (replicated across groups)
    for (int c = 0; c < CHUNKS; ++c) {
        // want G[i][col], i=l>>3, col=l&7 -> stored at (col*8 + i)
        const float g = gbuf[((long)(n * CHUNKS + c)) * 64 + ((l & 7) * 8 + (l >> 3))];
        const float nu = lse8(g + u);             // new_u[i], all lanes of group i
        u = __shfl(nu, ((l & 7) << 3) | (l >> 3)); // redistribute: u[col]
    }
    // u replicated 8x  ->  lse64(u) = log(8) + logsumexp_i u[i] = logZ
    const float z = lse64(u);
    if (l == 0) logZT[n] = z / (float)TT;
}

// ---------------- Kernel D: subtract logZ/T + cat-mod log_softmax --------
__global__ __launch_bounds__(256) void kD_final(float* __restrict__ out,
                                                const float* __restrict__ logZT) {
    const long row = (long)blockIdx.x * 256 + threadIdx.x;
    const int n = (int)(row & (NN - 1));
    const float z = logZT[n];
    float* orow = out + row * SOUT;
    float a[48];
#pragma unroll
    for (int i = 0; i < 12; ++i) {
        const float4 t = reinterpret_cast<const float4*>(orow)[i];
        a[4 * i] = t.x; a[4 * i + 1] = t.y; a[4 * i + 2] = t.z; a[4 * i + 3] = t.w;
    }
    const float y40 = a[40], y41 = a[41], y42 = a[42], y43 = a[43], y44 = a[44];
#pragma unroll
    for (int i = 0; i < 40; ++i) a[i] -= z;
    // group [0,1,2]
    const float m3 = fmaxf(fmaxf(y40, y41), y42);
    const float l3 = m3 + __logf(__expf(y40 - m3) + __expf(y41 - m3) + __expf(y42 - m3));
    a[40] = y40 - l3; a[41] = y41 - l3; a[42] = y42 - l3;
    // group [0,3]
    const float mA = fmaxf(y40, y43);
    const float lA = mA + __logf(__expf(y40 - mA) + __expf(y43 - mA));
    a[43] = y40 - lA; a[44] = y43 - lA;
    // group [0] -> log_softmax of singleton = 0
    a[45] = 0.f;
    // group [0,4]
    const float mB = fmaxf(y40, y44);
    const float lB = mB + __logf(__expf(y40 - mB) + __expf(y44 - mB));
    a[46] = y40 - lB; a[47] = y44 - lB;
#pragma unroll
    for (int i = 0; i < 12; ++i)
        reinterpret_cast<float4*>(orow)[i] =
            make_float4(a[4 * i], a[4 * i + 1], a[4 * i + 2], a[4 * i + 3]);
}

extern "C" void kernel_launch(void* const* d_in, const int* in_sizes, int n_in,
                              void* d_out, int out_size, void* d_ws, size_t ws_size,
                              hipStream_t stream) {
    const float* x = (const float*)d_in[0];
    const float* W = (const float*)d_in[1];
    const float* b = (const float*)d_in[2];
    float* out = (float*)d_out;
    float* gbuf  = (float*)d_ws;                 // 256*40*64 f32 = 2.62 MB
    float* logZT = gbuf + (long)NN * CHUNKS * 64; // 256 f32

    hipLaunchKernelGGL(kA_gemm, dim3((TT * NN) / 256), dim3(256), 0, stream, x, W, b, out);
    hipLaunchKernelGGL(kB_scan, dim3(NN, CHUNKS), dim3(64), 0, stream, out, gbuf);
    hipLaunchKernelGGL(kC_combine, dim3(NN), dim3(64), 0, stream, gbuf, logZT);
    hipLaunchKernelGGL(kD_final, dim3((TT * NN) / 256), dim3(256), 0, stream, out, logZT);
}

// Round 2
// 462.498 us; speedup vs baseline: 1.0922x; 1.0922x over previous
//
#include <hip/hip_runtime.h>
#include <hip/hip_bf16.h>
#include <math.h>

#define TT 2000
#define NN 256
#define DD 256
#define SS 45
#define SOUT 48
#define NTRANS_C 40
#define CHUNKS 40
#define CLEN 50   // TT / CHUNKS

typedef __attribute__((ext_vector_type(8))) short bf16x8;
typedef __attribute__((ext_vector_type(4))) float f32x4;

__device__ inline ushort f2bf(float f) {
    unsigned u = __float_as_uint(f);
    unsigned r = u + 0x7fffu + ((u >> 16) & 1u);
    return (ushort)(r >> 16);
}
__device__ inline float bf2f(ushort h) {
    return __uint_as_float(((unsigned)h) << 16);
}

// ---------------- Prep: split W into bf16 hi/lo, pad to 48 rows; pad b ----
__global__ __launch_bounds__(256) void kPrep(const float* __restrict__ W,
                                             const float* __restrict__ b,
                                             ushort* __restrict__ Whi,
                                             ushort* __restrict__ Wlo,
                                             float* __restrict__ b48) {
    const int s = blockIdx.x;   // 0..47
    const int k = threadIdx.x;  // 0..255
    const float wv = (s < SS) ? W[s * DD + k] : 0.f;
    const ushort h = f2bf(wv);
    Whi[s * DD + k] = h;
    Wlo[s * DD + k] = f2bf(wv - bf2f(h));
    if (k == 0) b48[s] = (s < SS) ? b[s] : 0.f;
}

// ---------------- Kernel A: split-bf16 MFMA GEMM + activations ------------
// 256 thr = 4 waves; wave = one 16-row M-tile x 48 cols; no LDS, no sync.
__global__ __launch_bounds__(256) void kA_mfma(const float* __restrict__ x,
                                               const ushort* __restrict__ Whi,
                                               const ushort* __restrict__ Wlo,
                                               const float* __restrict__ b48,
                                               float* __restrict__ out) {
    const int tid = threadIdx.x;
    const int l = tid & 63, w = tid >> 6;
    const long m0 = ((long)blockIdx.x * 4 + w) << 4;
    const int r16 = l & 15;   // A row / C col
    const int kg = l >> 4;    // k-group 0..3
    const float* xr = x + (m0 + r16) * DD + kg * 8;

    f32x4 acc[3] = {{0, 0, 0, 0}, {0, 0, 0, 0}, {0, 0, 0, 0}};

    for (int k0 = 0; k0 < DD; k0 += 32) {
        const float4 xa = *reinterpret_cast<const float4*>(xr + k0);
        const float4 xb = *reinterpret_cast<const float4*>(xr + k0 + 4);
        const float xf[8] = {xa.x, xa.y, xa.z, xa.w, xb.x, xb.y, xb.z, xb.w};
        bf16x8 ahi, alo;
#pragma unroll
        for (int e = 0; e < 8; ++e) {
            const ushort h = f2bf(xf[e]);
            ahi[e] = (short)h;
            alo[e] = (short)f2bf(xf[e] - bf2f(h));
        }
        const int koff = k0 + kg * 8;
#pragma unroll
        for (int jt = 0; jt < 3; ++jt) {
            const bf16x8 bhi = *reinterpret_cast<const bf16x8*>(Whi + (jt * 16 + r16) * DD + koff);
            const bf16x8 blo = *reinterpret_cast<const bf16x8*>(Wlo + (jt * 16 + r16) * DD + koff);
            acc[jt] = __builtin_amdgcn_mfma_f32_16x16x32_bf16(ahi, bhi, acc[jt], 0, 0, 0);
            acc[jt] = __builtin_amdgcn_mfma_f32_16x16x32_bf16(alo, bhi, acc[jt], 0, 0, 0);
            acc[jt] = __builtin_amdgcn_mfma_f32_16x16x32_bf16(ahi, blo, acc[jt], 0, 0, 0);
        }
    }
    // epilogue: C layout col=lane&15, row=(lane>>4)*4+reg  [m89]
#pragma unroll
    for (int jt = 0; jt < 3; ++jt) {
        const int col = jt * 16 + r16;
        const float bias = b48[col];
#pragma unroll
        for (int r = 0; r < 4; ++r) {
            const long orow = m0 + kg * 4 + r;
            const float y = acc[jt][r] + bias;
            float v;
            if (col < NTRANS_C) {
                const float e = __expf(2.f * y);
                v = 5.f * (1.f - 2.f / (e + 1.f));   // 5*tanh(y), saturates safely
            } else {
                v = y;
            }
            out[orow * SOUT + col] = v;
        }
    }
}

// ---------------- butterfly logsumexp helpers ----------------
__device__ inline float lse8(float v) {
    float m = v;
    m = fmaxf(m, __shfl_xor(m, 1));
    m = fmaxf(m, __shfl_xor(m, 2));
    m = fmaxf(m, __shfl_xor(m, 4));
    float e = __expf(v - m);
    e += __shfl_xor(e, 1);
    e += __shfl_xor(e, 2);
    e += __shfl_xor(e, 4);
    return m + __logf(e);
}

__device__ inline float lse64(float v) {
    float m = v;
#pragma unroll
    for (int d = 1; d < 64; d <<= 1) m = fmaxf(m, __shfl_xor(m, d));
    float e = __expf(v - m);
#pragma unroll
    for (int d = 1; d < 64; d <<= 1) e += __shfl_xor(e, d);
    return m + __logf(e);
}

// ---------------- Kernel B: per-(n,chunk) 8x8 log transfer matrix ----------
__global__ __launch_bounds__(64) void kB_scan(const float* __restrict__ out,
                                              float* __restrict__ gbuf) {
    const int n = blockIdx.x;
    const int c = blockIdx.y;
    const int l = threadIdx.x;
    const int col = l >> 3;
    const int j = l & 7;
    const int k = j & 3;
    float m = (j == col) ? 0.f : -1e30f;
    const int t0 = c * CLEN;
    for (int t = t0; t < t0 + CLEN; ++t) {
        const float* s = out + ((long)t * NN + n) * SOUT;
        const float s0 = s[j], s1 = s[8 + j], s2 = s[16 + j], s3 = s[24 + j];
        const float sa = s[32 + k], sb = s[36 + k];
        const float r0 = lse8(m + s0);
        const float r1 = lse8(m + s1);
        const float r2 = lse8(m + s2);
        const float r3 = lse8(m + s3);
        const float mk  = __shfl(m, (l & ~7) | k);
        const float mk4 = __shfl(m, (l & ~7) | (k + 4));
        const float pa = mk + sa, pb = mk4 + sb;
        const float mx = fmaxf(pa, pb);
        const float rb = mx + __logf(__expf(pa - mx) + __expf(pb - mx));
        const float rlow = (j < 2) ? ((j == 0) ? r0 : r1)
                                   : ((j == 2) ? r2 : r3);
        m = (j < 4) ? rlow : rb;
    }
    gbuf[((long)(n * CHUNKS + c)) * 64 + l] = m;
}

// ---------------- Kernel C: fold chunk matrices, emit logZ/T -------------
__global__ __launch_bounds__(64) void kC_combine(const float* __restrict__ gbuf,
                                                 float* __restrict__ logZT) {
    const int n = blockIdx.x;
    const int l = threadIdx.x;
    float u = -logf(8.f);
    for (int c = 0; c < CHUNKS; ++c) {
        const float g = gbuf[((long)(n * CHUNKS + c)) * 64 + ((l & 7) * 8 + (l >> 3))];
        const float nu = lse8(g + u);
        u = __shfl(nu, ((l & 7) << 3) | (l >> 3));
    }
    const float z = lse64(u);
    if (l == 0) logZT[n] = z / (float)TT;
}

// ---------------- Kernel D: subtract logZ/T + cat-mod log_softmax --------
__global__ __launch_bounds__(256) void kD_final(float* __restrict__ out,
                                                const float* __restrict__ logZT) {
    const long row = (long)blockIdx.x * 256 + threadIdx.x;
    const int n = (int)(row & (NN - 1));
    const float z = logZT[n];
    float* orow = out + row * SOUT;
    float a[48];
#pragma unroll
    for (int i = 0; i < 12; ++i) {
        const float4 t = reinterpret_cast<const float4*>(orow)[i];
        a[4 * i] = t.x; a[4 * i + 1] = t.y; a[4 * i + 2] = t.z; a[4 * i + 3] = t.w;
    }
    const float y40 = a[40], y41 = a[41], y42 = a[42], y43 = a[43], y44 = a[44];
#pragma unroll
    for (int i = 0; i < 40; ++i) a[i] -= z;
    const float m3 = fmaxf(fmaxf(y40, y41), y42);
    const float l3 = m3 + __logf(__expf(y40 - m3) + __expf(y41 - m3) + __expf(y42 - m3));
    a[40] = y40 - l3; a[41] = y41 - l3; a[42] = y42 - l3;
    const float mA = fmaxf(y40, y43);
    const float lA = mA + __logf(__expf(y40 - mA) + __expf(y43 - mA));
    a[43] = y40 - lA; a[44] = y43 - lA;
    a[45] = 0.f;
    const float mB = fmaxf(y40, y44);
    const float lB = mB + __logf(__expf(y40 - mB) + __expf(y44 - mB));
    a[46] = y40 - lB; a[47] = y44 - lB;
#pragma unroll
    for (int i = 0; i < 12; ++i)
        reinterpret_cast<float4*>(orow)[i] =
            make_float4(a[4 * i], a[4 * i + 1], a[4 * i + 2], a[4 * i + 3]);
}

extern "C" void kernel_launch(void* const* d_in, const int* in_sizes, int n_in,
                              void* d_out, int out_size, void* d_ws, size_t ws_size,
                              hipStream_t stream) {
    const float* x = (const float*)d_in[0];
    const float* W = (const float*)d_in[1];
    const float* b = (const float*)d_in[2];
    float* out = (float*)d_out;

    float* gbuf  = (float*)d_ws;                    // 256*40*64 f32 = 2.62 MB
    float* logZT = gbuf + (long)NN * CHUNKS * 64;   // 256 f32
    float* b48   = logZT + NN;                      // 48 f32
    ushort* Whi  = (ushort*)(b48 + SOUT);           // 48*256 u16
    ushort* Wlo  = Whi + SOUT * DD;                 // 48*256 u16

    hipLaunchKernelGGL(kPrep, dim3(SOUT), dim3(DD), 0, stream, W, b, Whi, Wlo, b48);
    hipLaunchKernelGGL(kA_mfma, dim3((TT * NN) / 64), dim3(256), 0, stream, x, Whi, Wlo, b48, out);
    hipLaunchKernelGGL(kB_scan, dim3(NN, CHUNKS), dim3(64), 0, stream, out, gbuf);
    hipLaunchKernelGGL(kC_combine, dim3(NN), dim3(64), 0, stream, gbuf, logZT);
    hipLaunchKernelGGL(kD_final, dim3((TT * NN) / 256), dim3(256), 0, stream, out, logZT);
}

// Round 3
// 336.776 us; speedup vs baseline: 1.5000x; 1.3733x over previous
//
#include <hip/hip_runtime.h>
#include <hip/hip_bf16.h>
#include <math.h>

#define TT 2000
#define NN 256
#define DD 256
#define SS 45
#define SOUT 48
#define NTRANS_C 40
#define CHUNKS 40
#define CLEN 50   // TT / CHUNKS

typedef __attribute__((ext_vector_type(8))) short bf16x8;
typedef __attribute__((ext_vector_type(4))) float f32x4;

__device__ inline ushort f2bf_rne(float f) {   // round-to-nearest-even (for W)
    unsigned u = __float_as_uint(f);
    unsigned r = u + 0x7fffu + ((u >> 16) & 1u);
    return (ushort)(r >> 16);
}

// ---------------- Prep: W -> bf16 (RNE), pad to 48 rows; pad b ----------
__global__ __launch_bounds__(256) void kPrep(const float* __restrict__ W,
                                             const float* __restrict__ b,
                                             ushort* __restrict__ Whi,
                                             float* __restrict__ b48) {
    const int s = blockIdx.x;   // 0..47
    const int k = threadIdx.x;  // 0..255
    const float wv = (s < SS) ? W[s * DD + k] : 0.f;
    Whi[s * DD + k] = f2bf_rne(wv);
    if (k == 0) b48[s] = (s < SS) ? b[s] : 0.f;
}

// ---------------- Kernel A: x-split bf16 MFMA GEMM + activations ----------
// (xhi + xlo) * Whi == x * Whi exactly; only error is dropped x*Wlo.
// 256 thr = 4 waves; wave = 16-row M-tile x 48 cols; no LDS, no sync.
__global__ __launch_bounds__(256) void kA_mfma(const float* __restrict__ x,
                                               const ushort* __restrict__ Whi,
                                               const float* __restrict__ b48,
                                               float* __restrict__ out) {
    const int tid = threadIdx.x;
    const int l = tid & 63, w = tid >> 6;
    const long m0 = ((long)blockIdx.x * 4 + w) << 4;
    const int r16 = l & 15;   // A row / C col
    const int kg = l >> 4;    // k-group 0..3
    const float* xr = x + (m0 + r16) * DD + kg * 8;

    f32x4 acc[3] = {{0, 0, 0, 0}, {0, 0, 0, 0}, {0, 0, 0, 0}};

#pragma unroll 4
    for (int k0 = 0; k0 < DD; k0 += 32) {
        const float4 xa = *reinterpret_cast<const float4*>(xr + k0);
        const float4 xb = *reinterpret_cast<const float4*>(xr + k0 + 4);
        const float xf[8] = {xa.x, xa.y, xa.z, xa.w, xb.x, xb.y, xb.z, xb.w};
        bf16x8 ahi, alo;
#pragma unroll
        for (int e = 0; e < 8; ++e) {
            const unsigned u = __float_as_uint(xf[e]);
            const float hi = __uint_as_float(u & 0xffff0000u);   // trunc bf16
            const float lo = xf[e] - hi;                          // exact
            ahi[e] = (short)(u >> 16);
            alo[e] = (short)(__float_as_uint(lo) >> 16);          // trunc, err ~2^-17
        }
        const int koff = k0 + kg * 8;
#pragma unroll
        for (int jt = 0; jt < 3; ++jt) {
            const bf16x8 bhi = *reinterpret_cast<const bf16x8*>(Whi + (jt * 16 + r16) * DD + koff);
            acc[jt] = __builtin_amdgcn_mfma_f32_16x16x32_bf16(ahi, bhi, acc[jt], 0, 0, 0);
            acc[jt] = __builtin_amdgcn_mfma_f32_16x16x32_bf16(alo, bhi, acc[jt], 0, 0, 0);
        }
    }
    // epilogue: C layout col=lane&15, row=(lane>>4)*4+reg  [m89]
#pragma unroll
    for (int jt = 0; jt < 3; ++jt) {
        const int col = jt * 16 + r16;
        const float bias = b48[col];
#pragma unroll
        for (int r = 0; r < 4; ++r) {
            const long orow = m0 + kg * 4 + r;
            const float y = acc[jt][r] + bias;
            float v;
            if (col < NTRANS_C) {
                const float e = __expf(2.f * y);
                v = 5.f * (1.f - 2.f / (e + 1.f));   // 5*tanh(y)
            } else {
                v = y;
            }
            out[orow * SOUT + col] = v;
        }
    }
}

// ---------------- Kernel B: per-(n,chunk) 8x8 log transfer matrix ----------
// lane = col*8 + j holds M[j][col]; shared-max exp formulation: 17 DS/step.
__global__ __launch_bounds__(64) void kB_scan(const float* __restrict__ out,
                                              float* __restrict__ gbuf) {
    const int n = blockIdx.x;
    const int c = blockIdx.y;
    const int l = threadIdx.x;
    const int col = l >> 3;
    const int j = l & 7;
    const int k = j & 3;
    float m = (j == col) ? 0.f : -1e30f;
    const int t0 = c * CLEN;
    for (int t = t0; t < t0 + CLEN; ++t) {
        const float* s = out + ((long)t * NN + n) * SOUT;
        const float s0 = s[j], s1 = s[8 + j], s2 = s[16 + j], s3 = s[24 + j];
        const float sa = s[32 + k], sb = s[36 + k];
        // shared group max over the 8 states of this column
        float Mx = m;
        Mx = fmaxf(Mx, __shfl_xor(Mx, 1));
        Mx = fmaxf(Mx, __shfl_xor(Mx, 2));
        Mx = fmaxf(Mx, __shfl_xor(Mx, 4));
        const float e = __expf(m - Mx);
        float p0 = e * __expf(s0);
        float p1 = e * __expf(s1);
        float p2 = e * __expf(s2);
        float p3 = e * __expf(s3);
#pragma unroll
        for (int d = 1; d < 8; d <<= 1) {
            p0 += __shfl_xor(p0, d);
            p1 += __shfl_xor(p1, d);
            p2 += __shfl_xor(p2, d);
            p3 += __shfl_xor(p3, d);
        }
        const float ek  = __shfl(e, (l & ~7) | k);
        const float ek4 = __shfl(e, (l & ~7) | (k + 4));
        const float Sb = ek * __expf(sa) + ek4 * __expf(sb);
        const float Slow = (j < 2) ? ((j == 0) ? p0 : p1)
                                   : ((j == 2) ? p2 : p3);
        const float S = (j < 4) ? Slow : Sb;
        m = Mx + __logf(S);
    }
    gbuf[((long)(n * CHUNKS + c)) * 64 + l] = m;
}

// ---------------- butterfly lse helpers for kC ----------------
__device__ inline float lse8(float v) {
    float m = v;
    m = fmaxf(m, __shfl_xor(m, 1));
    m = fmaxf(m, __shfl_xor(m, 2));
    m = fmaxf(m, __shfl_xor(m, 4));
    float e = __expf(v - m);
    e += __shfl_xor(e, 1);
    e += __shfl_xor(e, 2);
    e += __shfl_xor(e, 4);
    return m + __logf(e);
}

__device__ inline float lse64(float v) {
    float m = v;
#pragma unroll
    for (int d = 1; d < 64; d <<= 1) m = fmaxf(m, __shfl_xor(m, d));
    float e = __expf(v - m);
#pragma unroll
    for (int d = 1; d < 64; d <<= 1) e += __shfl_xor(e, d);
    return m + __logf(e);
}

// ---------------- Kernel C: fold chunk matrices, emit logZ/T -------------
__global__ __launch_bounds__(64) void kC_combine(const float* __restrict__ gbuf,
                                                 float* __restrict__ logZT) {
    const int n = blockIdx.x;
    const int l = threadIdx.x;
    float u = -logf(8.f);
    for (int c = 0; c < CHUNKS; ++c) {
        const float g = gbuf[((long)(n * CHUNKS + c)) * 64 + ((l & 7) * 8 + (l >> 3))];
        const float nu = lse8(g + u);
        u = __shfl(nu, ((l & 7) << 3) | (l >> 3));
    }
    const float z = lse64(u);
    if (l == 0) logZT[n] = z / (float)TT;
}

// ---------------- Kernel D: subtract logZ/T + cat-mod log_softmax --------
__global__ __launch_bounds__(256) void kD_final(float* __restrict__ out,
                                                const float* __restrict__ logZT) {
    const long row = (long)blockIdx.x * 256 + threadIdx.x;
    const int n = (int)(row & (NN - 1));
    const float z = logZT[n];
    float* orow = out + row * SOUT;
    float a[48];
#pragma unroll
    for (int i = 0; i < 12; ++i) {
        const float4 t = reinterpret_cast<const float4*>(orow)[i];
        a[4 * i] = t.x; a[4 * i + 1] = t.y; a[4 * i + 2] = t.z; a[4 * i + 3] = t.w;
    }
    const float y40 = a[40], y41 = a[41], y42 = a[42], y43 = a[43], y44 = a[44];
#pragma unroll
    for (int i = 0; i < 40; ++i) a[i] -= z;
    const float m3 = fmaxf(fmaxf(y40, y41), y42);
    const float l3 = m3 + __logf(__expf(y40 - m3) + __expf(y41 - m3) + __expf(y42 - m3));
    a[40] = y40 - l3; a[41] = y41 - l3; a[42] = y42 - l3;
    const float mA = fmaxf(y40, y43);
    const float lA = mA + __logf(__expf(y40 - mA) + __expf(y43 - mA));
    a[43] = y40 - lA; a[44] = y43 - lA;
    a[45] = 0.f;
    const float mB = fmaxf(y40, y44);
    const float lB = mB + __logf(__expf(y40 - mB) + __expf(y44 - mB));
    a[46] = y40 - lB; a[47] = y44 - lB;
#pragma unroll
    for (int i = 0; i < 12; ++i)
        reinterpret_cast<float4*>(orow)[i] =
            make_float4(a[4 * i], a[4 * i + 1], a[4 * i + 2], a[4 * i + 3]);
}

extern "C" void kernel_launch(void* const* d_in, const int* in_sizes, int n_in,
                              void* d_out, int out_size, void* d_ws, size_t ws_size,
                              hipStream_t stream) {
    const float* x = (const float*)d_in[0];
    const float* W = (const float*)d_in[1];
    const float* b = (const float*)d_in[2];
    float* out = (float*)d_out;

    float* gbuf  = (float*)d_ws;                    // 256*40*64 f32 = 2.62 MB
    float* logZT = gbuf + (long)NN * CHUNKS * 64;   // 256 f32
    float* b48   = logZT + NN;                      // 48 f32
    ushort* Whi  = (ushort*)(b48 + SOUT);           // 48*256 u16 = 24 KB

    hipLaunchKernelGGL(kPrep, dim3(SOUT), dim3(DD), 0, stream, W, b, Whi, b48);
    hipLaunchKernelGGL(kA_mfma, dim3((TT * NN) / 64), dim3(256), 0, stream, x, Whi, b48, out);
    hipLaunchKernelGGL(kB_scan, dim3(NN, CHUNKS), dim3(64), 0, stream, out, gbuf);
    hipLaunchKernelGGL(kC_combine, dim3(NN), dim3(64), 0, stream, gbuf, logZT);
    hipLaunchKernelGGL(kD_final, dim3((TT * NN) / 256), dim3(256), 0, stream, out, logZT);
}

// Round 4
// 289.375 us; speedup vs baseline: 1.7457x; 1.1638x over previous
//
#include <hip/hip_runtime.h>
#include <hip/hip_bf16.h>
#include <math.h>

#define TT 2000
#define NN 256
#define DD 256
#define SS 45
#define SOUT 48
#define NTRANS_C 40
#define CHUNKS 40
#define CLEN 50   // TT / CHUNKS

typedef __attribute__((ext_vector_type(8))) short bf16x8;
typedef __attribute__((ext_vector_type(4))) float f32x4;

__device__ inline ushort f2bf_rne(float f) {
    unsigned u = __float_as_uint(f);
    unsigned r = u + 0x7fffu + ((u >> 16) & 1u);
    return (ushort)(r >> 16);
}

// ---------------- Prep: W -> bf16 (RNE), pad to 48 rows; pad b ----------
__global__ __launch_bounds__(256) void kPrep(const float* __restrict__ W,
                                             const float* __restrict__ b,
                                             ushort* __restrict__ Whi,
                                             float* __restrict__ b48) {
    const int s = blockIdx.x;   // 0..47
    const int k = threadIdx.x;  // 0..255
    const float wv = (s < SS) ? W[s * DD + k] : 0.f;
    Whi[s * DD + k] = f2bf_rne(wv);
    if (k == 0) b48[s] = (s < SS) ? b[s] : 0.f;
}

// ---------------- Kernel A: bf16 MFMA GEMM + activations -----------------
// x cast to bf16 (RNE) in-register; W pre-converted (RNE). 3 MFMA / K-step.
__global__ __launch_bounds__(256, 4) void kA_mfma(const float* __restrict__ x,
                                                  const ushort* __restrict__ Whi,
                                                  const float* __restrict__ b48,
                                                  float* __restrict__ out) {
    const int tid = threadIdx.x;
    const int l = tid & 63, w = tid >> 6;
    const long m0 = ((long)blockIdx.x * 4 + w) << 4;
    const int r16 = l & 15;   // A row / C col
    const int kg = l >> 4;    // k-group 0..3
    const float* xr = x + (m0 + r16) * DD + kg * 8;
    const ushort* wp0 = Whi + (0 * 16 + r16) * DD + kg * 8;
    const ushort* wp1 = Whi + (1 * 16 + r16) * DD + kg * 8;
    const ushort* wp2 = Whi + (2 * 16 + r16) * DD + kg * 8;

    f32x4 acc[3] = {{0, 0, 0, 0}, {0, 0, 0, 0}, {0, 0, 0, 0}};

#pragma unroll
    for (int k0 = 0; k0 < DD; k0 += 32) {
        const float4 xa = *reinterpret_cast<const float4*>(xr + k0);
        const float4 xb = *reinterpret_cast<const float4*>(xr + k0 + 4);
        const float xf[8] = {xa.x, xa.y, xa.z, xa.w, xb.x, xb.y, xb.z, xb.w};
        bf16x8 a;
#pragma unroll
        for (int e = 0; e < 8; ++e) {
            const __hip_bfloat16 h = __float2bfloat16(xf[e]);   // RNE, cvt_pk-fusable
            a[e] = *reinterpret_cast<const short*>(&h);
        }
        const bf16x8 b0 = *reinterpret_cast<const bf16x8*>(wp0 + k0);
        const bf16x8 b1 = *reinterpret_cast<const bf16x8*>(wp1 + k0);
        const bf16x8 b2 = *reinterpret_cast<const bf16x8*>(wp2 + k0);
        acc[0] = __builtin_amdgcn_mfma_f32_16x16x32_bf16(a, b0, acc[0], 0, 0, 0);
        acc[1] = __builtin_amdgcn_mfma_f32_16x16x32_bf16(a, b1, acc[1], 0, 0, 0);
        acc[2] = __builtin_amdgcn_mfma_f32_16x16x32_bf16(a, b2, acc[2], 0, 0, 0);
    }
    // epilogue: C layout col=lane&15, row=(lane>>4)*4+reg  [m89]
#pragma unroll
    for (int jt = 0; jt < 3; ++jt) {
        const int col = jt * 16 + r16;
        const float bias = b48[col];
#pragma unroll
        for (int r = 0; r < 4; ++r) {
            const long orow = m0 + kg * 4 + r;
            const float y = acc[jt][r] + bias;
            float v;
            if (col < NTRANS_C) {
                const float e = __expf(2.f * y);
                v = 5.f * (1.f - 2.f / (e + 1.f));   // 5*tanh(y)
            } else {
                v = y;
            }
            out[orow * SOUT + col] = v;
        }
    }
}

// ---------------- DPP / swizzle cross-lane helpers (8-lane groups) -------
#define DPP_XOR1 0xB1  // quad_perm(1,0,3,2)
#define DPP_XOR2 0x4E  // quad_perm(2,3,0,1)

__device__ inline float fmax_x1(float v) {
    const int d = __builtin_amdgcn_mov_dpp(__float_as_int(v), DPP_XOR1, 0xF, 0xF, true);
    return fmaxf(v, __int_as_float(d));
}
__device__ inline float fmax_x2(float v) {
    const int d = __builtin_amdgcn_mov_dpp(__float_as_int(v), DPP_XOR2, 0xF, 0xF, true);
    return fmaxf(v, __int_as_float(d));
}
__device__ inline float fmax_x4(float v) {
    const int d = __builtin_amdgcn_ds_swizzle(__float_as_int(v), 0x101F);
    return fmaxf(v, __int_as_float(d));
}
__device__ inline float add_x1(float v) {
    const int d = __builtin_amdgcn_mov_dpp(__float_as_int(v), DPP_XOR1, 0xF, 0xF, true);
    return v + __int_as_float(d);
}
__device__ inline float add_x2(float v) {
    const int d = __builtin_amdgcn_mov_dpp(__float_as_int(v), DPP_XOR2, 0xF, 0xF, true);
    return v + __int_as_float(d);
}
__device__ inline float add_x4(float v) {
    const int d = __builtin_amdgcn_ds_swizzle(__float_as_int(v), 0x101F);
    return v + __int_as_float(d);
}
__device__ inline float sum8(float v) { return add_x4(add_x2(add_x1(v))); }
__device__ inline float max8(float v) { return fmax_x4(fmax_x2(fmax_x1(v))); }
// lane' = (lane & ~7) | (lane & 3)            -> gather group-lane k
__device__ inline float gat_k(float v) {
    return __int_as_float(__builtin_amdgcn_ds_swizzle(__float_as_int(v), 0x001B));
}
// lane' = (lane & ~7) | 4 | (lane & 3)        -> gather group-lane k+4
__device__ inline float gat_k4(float v) {
    return __int_as_float(__builtin_amdgcn_ds_swizzle(__float_as_int(v), 0x009B));
}

// ---------------- Kernel B: per-(n,chunk) 8x8 log transfer matrix ----------
// lane = col*8 + j holds M[j][col]; 7 DS + 10 DPP ops/step; 2-deep prefetch.
__global__ __launch_bounds__(64) void kB_scan(const float* __restrict__ out,
                                              float* __restrict__ gbuf) {
    const int n = blockIdx.x;
    const int c = blockIdx.y;
    const int l = threadIdx.x;
    const int col = l >> 3;
    const int j = l & 7;
    const int k = j & 3;
    float m = (j == col) ? 0.f : -1e30f;
    const long stride = (long)NN * SOUT;
    const float* sp = out + ((long)(c * CLEN) * NN + n) * SOUT;

    float c0 = sp[j], c1 = sp[8 + j], c2 = sp[16 + j], c3 = sp[24 + j];
    float ca = sp[32 + k], cb = sp[36 + k];

    for (int t = 0; t < CLEN; ++t) {
        const float* np = sp + stride;
        float n0, n1, n2, n3, na, nb;
        if (t + 1 < CLEN) {   // issue next-step loads before the serial chain
            n0 = np[j]; n1 = np[8 + j]; n2 = np[16 + j]; n3 = np[24 + j];
            na = np[32 + k]; nb = np[36 + k];
        }
        const float Mx = max8(m);
        const float e = __expf(m - Mx);
        const float p0 = sum8(e * __expf(c0));
        const float p1 = sum8(e * __expf(c1));
        const float p2 = sum8(e * __expf(c2));
        const float p3 = sum8(e * __expf(c3));
        const float Sb = fmaf(gat_k(e), __expf(ca), gat_k4(e) * __expf(cb));
        const float Slow = (j < 2) ? ((j == 0) ? p0 : p1)
                                   : ((j == 2) ? p2 : p3);
        const float S = (j < 4) ? Slow : Sb;
        m = Mx + __logf(S);
        c0 = n0; c1 = n1; c2 = n2; c3 = n3; ca = na; cb = nb;
        sp = np;
    }
    gbuf[((long)(n * CHUNKS + c)) * 64 + l] = m;
}

// ---------------- butterfly lse helpers for kC ----------------
__device__ inline float lse8(float v) {
    const float m = max8(v);
    return m + __logf(sum8(__expf(v - m)));
}
__device__ inline float lse64(float v) {
    float m = v;
#pragma unroll
    for (int d = 1; d < 64; d <<= 1) m = fmaxf(m, __shfl_xor(m, d));
    float e = __expf(v - m);
#pragma unroll
    for (int d = 1; d < 64; d <<= 1) e += __shfl_xor(e, d);
    return m + __logf(e);
}

// ---------------- Kernel C: fold chunk matrices, emit logZ/T -------------
__global__ __launch_bounds__(64) void kC_combine(const float* __restrict__ gbuf,
                                                 float* __restrict__ logZT) {
    const int n = blockIdx.x;
    const int l = threadIdx.x;
    const int gi = (l & 7) * 8 + (l >> 3);
    float g[CHUNKS];
#pragma unroll
    for (int c = 0; c < CHUNKS; ++c)     // all loads issue up front
        g[c] = gbuf[((long)(n * CHUNKS + c)) * 64 + gi];
    float u = -logf(8.f);
#pragma unroll
    for (int c = 0; c < CHUNKS; ++c) {
        const float nu = lse8(g[c] + u);
        u = __shfl(nu, ((l & 7) << 3) | (l >> 3));
    }
    const float z = lse64(u);
    if (l == 0) logZT[n] = z / (float)TT;
}

// ---------------- Kernel D: subtract logZ/T + cat-mod log_softmax --------
__global__ __launch_bounds__(256) void kD_final(float* __restrict__ out,
                                                const float* __restrict__ logZT) {
    const long row = (long)blockIdx.x * 256 + threadIdx.x;
    const int n = (int)(row & (NN - 1));
    const float z = logZT[n];
    float* orow = out + row * SOUT;
    float a[48];
#pragma unroll
    for (int i = 0; i < 12; ++i) {
        const float4 t = reinterpret_cast<const float4*>(orow)[i];
        a[4 * i] = t.x; a[4 * i + 1] = t.y; a[4 * i + 2] = t.z; a[4 * i + 3] = t.w;
    }
    const float y40 = a[40], y41 = a[41], y42 = a[42], y43 = a[43], y44 = a[44];
#pragma unroll
    for (int i = 0; i < 40; ++i) a[i] -= z;
    const float m3 = fmaxf(fmaxf(y40, y41), y42);
    const float l3 = m3 + __logf(__expf(y40 - m3) + __expf(y41 - m3) + __expf(y42 - m3));
    a[40] = y40 - l3; a[41] = y41 - l3; a[42] = y42 - l3;
    const float mA = fmaxf(y40, y43);
    const float lA = mA + __logf(__expf(y40 - mA) + __expf(y43 - mA));
    a[43] = y40 - lA; a[44] = y43 - lA;
    a[45] = 0.f;
    const float mB = fmaxf(y40, y44);
    const float lB = mB + __logf(__expf(y40 - mB) + __expf(y44 - mB));
    a[46] = y40 - lB; a[47] = y44 - lB;
#pragma unroll
    for (int i = 0; i < 12; ++i)
        reinterpret_cast<float4*>(orow)[i] =
            make_float4(a[4 * i], a[4 * i + 1], a[4 * i + 2], a[4 * i + 3]);
}

extern "C" void kernel_launch(void* const* d_in, const int* in_sizes, int n_in,
                              void* d_out, int out_size, void* d_ws, size_t ws_size,
                              hipStream_t stream) {
    const float* x = (const float*)d_in[0];
    const float* W = (const float*)d_in[1];
    const float* b = (const float*)d_in[2];
    float* out = (float*)d_out;

    float* gbuf  = (float*)d_ws;                    // 256*40*64 f32 = 2.62 MB
    float* logZT = gbuf + (long)NN * CHUNKS * 64;   // 256 f32
    float* b48   = logZT + NN;                      // 48 f32
    ushort* Whi  = (ushort*)(b48 + SOUT);           // 48*256 u16 = 24 KB

    hipLaunchKernelGGL(kPrep, dim3(SOUT), dim3(DD), 0, stream, W, b, Whi, b48);
    hipLaunchKernelGGL(kA_mfma, dim3((TT * NN) / 64), dim3(256), 0, stream, x, Whi, b48, out);
    hipLaunchKernelGGL(kB_scan, dim3(NN, CHUNKS), dim3(64), 0, stream, out, gbuf);
    hipLaunchKernelGGL(kC_combine, dim3(NN), dim3(64), 0, stream, gbuf, logZT);
    hipLaunchKernelGGL(kD_final, dim3((TT * NN) / 256), dim3(256), 0, stream, out, logZT);
}

// Round 5
// 276.643 us; speedup vs baseline: 1.8260x; 1.0460x over previous
//
#include <hip/hip_runtime.h>
#include <hip/hip_bf16.h>
#include <math.h>

#define TT 2000
#define NN 256
#define DD 256
#define SS 45
#define SOUT 48
#define NTRANS_C 40
#define CHUNKS 40
#define CLEN 50   // TT / CHUNKS

typedef __attribute__((ext_vector_type(8))) short bf16x8;
typedef __attribute__((ext_vector_type(4))) float f32x4;
typedef __attribute__((ext_vector_type(4))) int i32x4;

__device__ inline ushort f2bf_rne(float f) {
    unsigned u = __float_as_uint(f);
    unsigned r = u + 0x7fffu + ((u >> 16) & 1u);
    return (ushort)(r >> 16);
}
__device__ inline int pkbf(float lo, float hi) {
    return (int)((unsigned)f2bf_rne(lo) | ((unsigned)f2bf_rne(hi) << 16));
}

// ---------------- Prep: W -> bf16 (RNE), pad to 48 rows; pad b ----------
__global__ __launch_bounds__(256) void kPrep(const float* __restrict__ W,
                                             const float* __restrict__ b,
                                             ushort* __restrict__ Whi,
                                             float* __restrict__ b48) {
    const int s = blockIdx.x;   // 0..47
    const int k = threadIdx.x;  // 0..255
    const float wv = (s < SS) ? W[s * DD + k] : 0.f;
    Whi[s * DD + k] = f2bf_rne(wv);
    if (k == 0) b48[s] = (s < SS) ? b[s] : 0.f;
}

// ---------------- Kernel A: bf16 MFMA GEMM + activations -----------------
// Contiguous x loads (8 full lines / instr) + ds_bpermute redistribution
// into the fixed A-fragment layout. No LDS buffer, no barriers.
__global__ __launch_bounds__(256, 4) void kA_mfma(const float* __restrict__ x,
                                                  const ushort* __restrict__ Whi,
                                                  const float* __restrict__ b48,
                                                  float* __restrict__ out) {
    const int tid = threadIdx.x;
    const int l = tid & 63, w = tid >> 6;
    const long m0 = ((long)blockIdx.x * 4 + w) << 4;
    const int r16 = l & 15;   // A row / C col
    const int kg = l >> 4;    // k-group 0..3
    // loader mapping: lane covers rows (l>>3) and 8+(l>>3), 16B at (l&7)*16
    const float* xp = x + (m0 + (l >> 3)) * DD + (l & 7) * 4;
    const float* xq = xp + 8 * DD;
    const ushort* wp0 = Whi + (0 * 16 + r16) * DD + kg * 8;
    const ushort* wp1 = Whi + (1 * 16 + r16) * DD + kg * 8;
    const ushort* wp2 = Whi + (2 * 16 + r16) * DD + kg * 8;
    // bpermute source byte-indices: frag lane needs src lanes s0, s0+1
    const int s0 = (((l & 7) * 8 + kg * 2) << 2);
    const int s1 = s0 + 4;
    const bool hi = (l & 8) != 0;   // rows 8-15 come from the q-set

    f32x4 acc[3] = {{0, 0, 0, 0}, {0, 0, 0, 0}, {0, 0, 0, 0}};

#pragma unroll
    for (int k0 = 0; k0 < DD; k0 += 32) {
        const float4 pa = *reinterpret_cast<const float4*>(xp + k0);
        const float4 qa = *reinterpret_cast<const float4*>(xq + k0);
        const int pA = pkbf(pa.x, pa.y), pB = pkbf(pa.z, pa.w);
        const int qA = pkbf(qa.x, qa.y), qB = pkbf(qa.z, qa.w);
        const int f0p = __builtin_amdgcn_ds_bpermute(s0, pA);
        const int f1p = __builtin_amdgcn_ds_bpermute(s0, pB);
        const int f2p = __builtin_amdgcn_ds_bpermute(s1, pA);
        const int f3p = __builtin_amdgcn_ds_bpermute(s1, pB);
        const int f0q = __builtin_amdgcn_ds_bpermute(s0, qA);
        const int f1q = __builtin_amdgcn_ds_bpermute(s0, qB);
        const int f2q = __builtin_amdgcn_ds_bpermute(s1, qA);
        const int f3q = __builtin_amdgcn_ds_bpermute(s1, qB);
        i32x4 av;
        av[0] = hi ? f0q : f0p;
        av[1] = hi ? f1q : f1p;
        av[2] = hi ? f2q : f2p;
        av[3] = hi ? f3q : f3p;
        const bf16x8 a = __builtin_bit_cast(bf16x8, av);
        const bf16x8 b0 = *reinterpret_cast<const bf16x8*>(wp0 + k0);
        const bf16x8 b1 = *reinterpret_cast<const bf16x8*>(wp1 + k0);
        const bf16x8 b2 = *reinterpret_cast<const bf16x8*>(wp2 + k0);
        acc[0] = __builtin_amdgcn_mfma_f32_16x16x32_bf16(a, b0, acc[0], 0, 0, 0);
        acc[1] = __builtin_amdgcn_mfma_f32_16x16x32_bf16(a, b1, acc[1], 0, 0, 0);
        acc[2] = __builtin_amdgcn_mfma_f32_16x16x32_bf16(a, b2, acc[2], 0, 0, 0);
    }
    // epilogue: C layout col=lane&15, row=(lane>>4)*4+reg  [m89]
#pragma unroll
    for (int jt = 0; jt < 3; ++jt) {
        const int col = jt * 16 + r16;
        const float bias = b48[col];
#pragma unroll
        for (int r = 0; r < 4; ++r) {
            const long orow = m0 + kg * 4 + r;
            const float y = acc[jt][r] + bias;
            float v;
            if (col < NTRANS_C) {
                const float e = __expf(2.f * y);
                v = 5.f * (1.f - 2.f / (e + 1.f));   // 5*tanh(y)
            } else {
                v = y;
            }
            out[orow * SOUT + col] = v;
        }
    }
}

// ---------------- DPP / swizzle cross-lane helpers -----------------------
#define DPP_XOR1 0xB1  // quad_perm(1,0,3,2)
#define DPP_XOR2 0x4E  // quad_perm(2,3,0,1)

__device__ inline float fmax_x1(float v) {
    const int d = __builtin_amdgcn_mov_dpp(__float_as_int(v), DPP_XOR1, 0xF, 0xF, true);
    return fmaxf(v, __int_as_float(d));
}
__device__ inline float fmax_x2(float v) {
    const int d = __builtin_amdgcn_mov_dpp(__float_as_int(v), DPP_XOR2, 0xF, 0xF, true);
    return fmaxf(v, __int_as_float(d));
}
__device__ inline float add_x1(float v) {
    const int d = __builtin_amdgcn_mov_dpp(__float_as_int(v), DPP_XOR1, 0xF, 0xF, true);
    return v + __int_as_float(d);
}
__device__ inline float add_x2(float v) {
    const int d = __builtin_amdgcn_mov_dpp(__float_as_int(v), DPP_XOR2, 0xF, 0xF, true);
    return v + __int_as_float(d);
}
__device__ inline float swz4(float v) {   // lane ^ 4
    return __int_as_float(__builtin_amdgcn_ds_swizzle(__float_as_int(v), 0x101F));
}
__device__ inline float fmax_x4(float v) { return fmaxf(v, swz4(v)); }
__device__ inline float add_x4(float v) { return v + swz4(v); }
__device__ inline float sum8(float v) { return add_x4(add_x2(add_x1(v))); }
__device__ inline float max8(float v) { return fmax_x4(fmax_x2(fmax_x1(v))); }
// lane' = (lane & ~7) | (lane & 3)  -> gather group-lane k (lo quad of oct)
__device__ inline float gat_k(float v) {
    return __int_as_float(__builtin_amdgcn_ds_swizzle(__float_as_int(v), 0x001B));
}

// ---------------- Kernel B: per-(n,chunk) 8x8 log transfer matrix ----------
// lane = col*8 + j holds M[j][col]. Quad-local max + cross-quad scale fix:
// single LDS-latency on the serial chain; score-exps hoisted off it.
__global__ __launch_bounds__(64) void kB_scan(const float* __restrict__ out,
                                              float* __restrict__ gbuf) {
    const int n = blockIdx.x;
    const int c = blockIdx.y;
    const int l = threadIdx.x;
    const int col = l >> 3;
    const int j = l & 7;
    const int k = j & 3;
    float m = (j == col) ? 0.f : -60.f;   // finite "-inf": e^-60 is negligible
    const long stride = (long)NN * SOUT;
    const float* sp = out + ((long)(c * CLEN) * NN + n) * SOUT;

    float c0 = sp[j], c1 = sp[8 + j], c2 = sp[16 + j], c3 = sp[24 + j];
    float ca = sp[32 + k], cb = sp[36 + k];

    for (int t = 0; t < CLEN; ++t) {
        const float* np = sp + stride;
        float n0, n1, n2, n3, na, nb;
        if (t + 1 < CLEN) {   // prefetch next step's scores
            n0 = np[j]; n1 = np[8 + j]; n2 = np[16 + j]; n3 = np[24 + j];
            na = np[32 + k]; nb = np[36 + k];
        }
        // hoisted: depends only on loaded scores
        const float E0 = __expf(c0), E1 = __expf(c1), E2 = __expf(c2), E3 = __expf(c3);
        const float Ea = __expf(ca), Eb = __expf(cb);
        // serial chain
        const float Mq = fmax_x2(fmax_x1(m));   // quad-local max (2 DPP)
        const float MqX = swz4(Mq);             // other quad's max (parallel)
        const float e = __expf(m - Mq);
        const float corr = __expf(MqX - Mq);    // cross-quad rescale
        const float p0l = add_x2(add_x1(e * E0));
        const float p1l = add_x2(add_x1(e * E1));
        const float p2l = add_x2(add_x1(e * E2));
        const float p3l = add_x2(add_x1(e * E3));
        const float p0 = fmaf(corr, swz4(p0l), p0l);
        const float p1 = fmaf(corr, swz4(p1l), p1l);
        const float p2 = fmaf(corr, swz4(p2l), p2l);
        const float p3 = fmaf(corr, swz4(p3l), p3l);
        // base2 (j>=4): new[4+k] = e_k*corr*Ea + e_{k+4}*Eb  (e_{k+4} is own e)
        const float Sb = fmaf(corr * gat_k(e), Ea, e * Eb);
        const float Slow = (j < 2) ? ((j == 0) ? p0 : p1)
                                   : ((j == 2) ? p2 : p3);
        const float S = (j < 4) ? Slow : Sb;
        m = Mq + __logf(S);
        c0 = n0; c1 = n1; c2 = n2; c3 = n3; ca = na; cb = nb;
        sp = np;
    }
    gbuf[((long)(n * CHUNKS + c)) * 64 + l] = m;
}

// ---------------- butterfly lse helpers for kC ----------------
__device__ inline float lse8(float v) {
    const float m = max8(v);
    return m + __logf(sum8(__expf(v - m)));
}
__device__ inline float lse64(float v) {
    float m = v;
#pragma unroll
    for (int d = 1; d < 64; d <<= 1) m = fmaxf(m, __shfl_xor(m, d));
    float e = __expf(v - m);
#pragma unroll
    for (int d = 1; d < 64; d <<= 1) e += __shfl_xor(e, d);
    return m + __logf(e);
}

// ---------------- Kernel C: fold chunk matrices, emit logZ/T -------------
__global__ __launch_bounds__(64) void kC_combine(const float* __restrict__ gbuf,
                                                 float* __restrict__ logZT) {
    const int n = blockIdx.x;
    const int l = threadIdx.x;
    const int gi = (l & 7) * 8 + (l >> 3);
    float g[CHUNKS];
#pragma unroll
    for (int c = 0; c < CHUNKS; ++c)     // all loads issue up front
        g[c] = gbuf[((long)(n * CHUNKS + c)) * 64 + gi];
    float u = -logf(8.f);
#pragma unroll
    for (int c = 0; c < CHUNKS; ++c) {
        const float nu = lse8(g[c] + u);
        u = __shfl(nu, ((l & 7) << 3) | (l >> 3));
    }
    const float z = lse64(u);
    if (l == 0) logZT[n] = z / (float)TT;
}

// ---------------- Kernel D: subtract logZ/T + cat-mod log_softmax --------
__global__ __launch_bounds__(256) void kD_final(float* __restrict__ out,
                                                const float* __restrict__ logZT) {
    const long row = (long)blockIdx.x * 256 + threadIdx.x;
    const int n = (int)(row & (NN - 1));
    const float z = logZT[n];
    float* orow = out + row * SOUT;
    float a[48];
#pragma unroll
    for (int i = 0; i < 12; ++i) {
        const float4 t = reinterpret_cast<const float4*>(orow)[i];
        a[4 * i] = t.x; a[4 * i + 1] = t.y; a[4 * i + 2] = t.z; a[4 * i + 3] = t.w;
    }
    const float y40 = a[40], y41 = a[41], y42 = a[42], y43 = a[43], y44 = a[44];
#pragma unroll
    for (int i = 0; i < 40; ++i) a[i] -= z;
    const float m3 = fmaxf(fmaxf(y40, y41), y42);
    const float l3 = m3 + __logf(__expf(y40 - m3) + __expf(y41 - m3) + __expf(y42 - m3));
    a[40] = y40 - l3; a[41] = y41 - l3; a[42] = y42 - l3;
    const float mA = fmaxf(y40, y43);
    const float lA = mA + __logf(__expf(y40 - mA) + __expf(y43 - mA));
    a[43] = y40 - lA; a[44] = y43 - lA;
    a[45] = 0.f;
    const float mB = fmaxf(y40, y44);
    const float lB = mB + __logf(__expf(y40 - mB) + __expf(y44 - mB));
    a[46] = y40 - lB; a[47] = y44 - lB;
#pragma unroll
    for (int i = 0; i < 12; ++i)
        reinterpret_cast<float4*>(orow)[i] =
            make_float4(a[4 * i], a[4 * i + 1], a[4 * i + 2], a[4 * i + 3]);
}

extern "C" void kernel_launch(void* const* d_in, const int* in_sizes, int n_in,
                              void* d_out, int out_size, void* d_ws, size_t ws_size,
                              hipStream_t stream) {
    const float* x = (const float*)d_in[0];
    const float* W = (const float*)d_in[1];
    const float* b = (const float*)d_in[2];
    float* out = (float*)d_out;

    float* gbuf  = (float*)d_ws;                    // 256*40*64 f32 = 2.62 MB
    float* logZT = gbuf + (long)NN * CHUNKS * 64;   // 256 f32
    float* b48   = logZT + NN;                      // 48 f32
    ushort* Whi  = (ushort*)(b48 + SOUT);           // 48*256 u16 = 24 KB

    hipLaunchKernelGGL(kPrep, dim3(SOUT), dim3(DD), 0, stream, W, b, Whi, b48);
    hipLaunchKernelGGL(kA_mfma, dim3((TT * NN) / 64), dim3(256), 0, stream, x, Whi, b48, out);
    hipLaunchKernelGGL(kB_scan, dim3(NN, CHUNKS), dim3(64), 0, stream, out, gbuf);
    hipLaunchKernelGGL(kC_combine, dim3(NN), dim3(64), 0, stream, gbuf, logZT);
    hipLaunchKernelGGL(kD_final, dim3((TT * NN) / 256), dim3(256), 0, stream, out, logZT);
}

// Round 6
// 266.098 us; speedup vs baseline: 1.8984x; 1.0396x over previous
//
#include <hip/hip_runtime.h>
#include <hip/hip_bf16.h>
#include <math.h>

#define TT 2000
#define NN 256
#define DD 256
#define SS 45
#define SOUT 48
#define NTRANS_C 40
#define CHUNKS 40
#define CLEN 50   // TT / CHUNKS

typedef __attribute__((ext_vector_type(8))) short bf16x8;
typedef __attribute__((ext_vector_type(4))) float f32x4;
typedef __attribute__((ext_vector_type(4))) int i32x4;

__device__ inline ushort f2bf_rne(float f) {
    unsigned u = __float_as_uint(f);
    unsigned r = u + 0x7fffu + ((u >> 16) & 1u);
    return (ushort)(r >> 16);
}
__device__ inline int pkbf(float lo, float hi) {
    return (int)((unsigned)f2bf_rne(lo) | ((unsigned)f2bf_rne(hi) << 16));
}
// storage permutation for the score buffer (see theory):
//  c<32 (trans blk 0..3): -> 4*j + blk ; c in 32..39 (trans blk 4): pairs
//  (32+k,36+k) -> (32+2k, 32+2k+1) ; c>=40 (cat) unchanged.
__device__ __host__ __forceinline__ constexpr int sidx(int c) {
    return (c < 32) ? (4 * (c & 7) + (c >> 3))
         : (c < 36) ? (32 + 2 * (c - 32))
         : (c < 40) ? (32 + 2 * (c - 36) + 1)
         : c;
}

// ---------------- Prep: W -> bf16 (RNE), pad to 48 rows; pad b ----------
__global__ __launch_bounds__(256) void kPrep(const float* __restrict__ W,
                                             const float* __restrict__ b,
                                             ushort* __restrict__ Whi,
                                             float* __restrict__ b48) {
    const int s = blockIdx.x;   // 0..47
    const int k = threadIdx.x;  // 0..255
    const float wv = (s < SS) ? W[s * DD + k] : 0.f;
    Whi[s * DD + k] = f2bf_rne(wv);
    if (k == 0) b48[s] = (s < SS) ? b[s] : 0.f;
}

// ---------------- Kernel A: bf16 MFMA GEMM + activations -----------------
// Contiguous x loads + ds_bpermute redistribution into the A-fragment
// layout. Scores written bf16 into the permuted ws buffer.
__global__ __launch_bounds__(256, 4) void kA_mfma(const float* __restrict__ x,
                                                  const ushort* __restrict__ Whi,
                                                  const float* __restrict__ b48,
                                                  ushort* __restrict__ sc) {
    const int tid = threadIdx.x;
    const int l = tid & 63, w = tid >> 6;
    const long m0 = ((long)blockIdx.x * 4 + w) << 4;
    const int r16 = l & 15;   // A row / C col
    const int kg = l >> 4;    // k-group 0..3
    const float* xp = x + (m0 + (l >> 3)) * DD + (l & 7) * 4;
    const float* xq = xp + 8 * DD;
    const ushort* wp0 = Whi + (0 * 16 + r16) * DD + kg * 8;
    const ushort* wp1 = Whi + (1 * 16 + r16) * DD + kg * 8;
    const ushort* wp2 = Whi + (2 * 16 + r16) * DD + kg * 8;
    const int s0 = (((l & 7) * 8 + kg * 2) << 2);
    const int s1 = s0 + 4;
    const bool hi = (l & 8) != 0;

    f32x4 acc[3] = {{0, 0, 0, 0}, {0, 0, 0, 0}, {0, 0, 0, 0}};

#pragma unroll
    for (int k0 = 0; k0 < DD; k0 += 32) {
        const float4 pa = *reinterpret_cast<const float4*>(xp + k0);
        const float4 qa = *reinterpret_cast<const float4*>(xq + k0);
        const int pA = pkbf(pa.x, pa.y), pB = pkbf(pa.z, pa.w);
        const int qA = pkbf(qa.x, qa.y), qB = pkbf(qa.z, qa.w);
        const int f0p = __builtin_amdgcn_ds_bpermute(s0, pA);
        const int f1p = __builtin_amdgcn_ds_bpermute(s0, pB);
        const int f2p = __builtin_amdgcn_ds_bpermute(s1, pA);
        const int f3p = __builtin_amdgcn_ds_bpermute(s1, pB);
        const int f0q = __builtin_amdgcn_ds_bpermute(s0, qA);
        const int f1q = __builtin_amdgcn_ds_bpermute(s0, qB);
        const int f2q = __builtin_amdgcn_ds_bpermute(s1, qA);
        const int f3q = __builtin_amdgcn_ds_bpermute(s1, qB);
        i32x4 av;
        av[0] = hi ? f0q : f0p;
        av[1] = hi ? f1q : f1p;
        av[2] = hi ? f2q : f2p;
        av[3] = hi ? f3q : f3p;
        const bf16x8 a = __builtin_bit_cast(bf16x8, av);
        const bf16x8 b0 = *reinterpret_cast<const bf16x8*>(wp0 + k0);
        const bf16x8 b1 = *reinterpret_cast<const bf16x8*>(wp1 + k0);
        const bf16x8 b2 = *reinterpret_cast<const bf16x8*>(wp2 + k0);
        acc[0] = __builtin_amdgcn_mfma_f32_16x16x32_bf16(a, b0, acc[0], 0, 0, 0);
        acc[1] = __builtin_amdgcn_mfma_f32_16x16x32_bf16(a, b1, acc[1], 0, 0, 0);
        acc[2] = __builtin_amdgcn_mfma_f32_16x16x32_bf16(a, b2, acc[2], 0, 0, 0);
    }
    // epilogue: C layout col=lane&15, row=(lane>>4)*4+reg  [m89]
#pragma unroll
    for (int jt = 0; jt < 3; ++jt) {
        const int col = jt * 16 + r16;
        const float bias = b48[col];
        int si;
        if (jt < 2) si = 4 * (col & 7) + (col >> 3);
        else if (r16 < 8) si = (r16 < 4) ? (32 + 2 * r16) : (32 + 2 * (r16 - 4) + 1);
        else si = 40 + (r16 - 8);
#pragma unroll
        for (int r = 0; r < 4; ++r) {
            const long orow = m0 + kg * 4 + r;
            const float y = acc[jt][r] + bias;
            float v;
            if (col < NTRANS_C) {
                const float e = __expf(2.f * y);
                v = 5.f * (1.f - 2.f / (e + 1.f));   // 5*tanh(y)
            } else {
                v = y;
            }
            sc[orow * SOUT + si] = f2bf_rne(v);
        }
    }
}

// ---------------- DPP / swizzle cross-lane helpers -----------------------
#define DPP_XOR1 0xB1  // quad_perm(1,0,3,2)
#define DPP_XOR2 0x4E  // quad_perm(2,3,0,1)

__device__ inline float fmax_x1(float v) {
    const int d = __builtin_amdgcn_mov_dpp(__float_as_int(v), DPP_XOR1, 0xF, 0xF, true);
    return fmaxf(v, __int_as_float(d));
}
__device__ inline float fmax_x2(float v) {
    const int d = __builtin_amdgcn_mov_dpp(__float_as_int(v), DPP_XOR2, 0xF, 0xF, true);
    return fmaxf(v, __int_as_float(d));
}
__device__ inline float add_x1(float v) {
    const int d = __builtin_amdgcn_mov_dpp(__float_as_int(v), DPP_XOR1, 0xF, 0xF, true);
    return v + __int_as_float(d);
}
__device__ inline float add_x2(float v) {
    const int d = __builtin_amdgcn_mov_dpp(__float_as_int(v), DPP_XOR2, 0xF, 0xF, true);
    return v + __int_as_float(d);
}
__device__ inline float swz4(float v) {   // lane ^ 4
    return __int_as_float(__builtin_amdgcn_ds_swizzle(__float_as_int(v), 0x101F));
}
__device__ inline float fmax_x4(float v) { return fmaxf(v, swz4(v)); }
__device__ inline float add_x4(float v) { return v + swz4(v); }
__device__ inline float sum8(float v) { return add_x4(add_x2(add_x1(v))); }
__device__ inline float max8(float v) { return fmax_x4(fmax_x2(fmax_x1(v))); }
// lane' = (lane & ~7) | (lane & 3)  -> gather group-lane k
__device__ inline float gat_k(float v) {
    return __int_as_float(__builtin_amdgcn_ds_swizzle(__float_as_int(v), 0x001B));
}

// ---------------- Kernel B: per-(n,chunk) 8x8 log transfer matrix ----------
// bf16 permuted scores: one b64 + one b32 load per step.
__global__ __launch_bounds__(64) void kB_scan(const ushort* __restrict__ sc,
                                              float* __restrict__ gbuf) {
    const int n = blockIdx.x;
    const int c = blockIdx.y;
    const int l = threadIdx.x;
    const int col = l >> 3;
    const int j = l & 7;
    const int k = j & 3;
    float m = (j == col) ? 0.f : -60.f;   // finite "-inf"
    const long stride = (long)NN * SOUT;  // in u16 elements
    const ushort* sp = sc + ((long)(c * CLEN) * NN + n) * SOUT;

    uint2 dv = *reinterpret_cast<const uint2*>(sp + 4 * j);
    unsigned dab = *reinterpret_cast<const unsigned*>(sp + 32 + 2 * k);

    for (int t = 0; t < CLEN; ++t) {
        const ushort* np = sp + stride;
        uint2 nv;
        unsigned nab;
        if (t + 1 < CLEN) {   // prefetch next step's scores
            nv = *reinterpret_cast<const uint2*>(np + 4 * j);
            nab = *reinterpret_cast<const unsigned*>(np + 32 + 2 * k);
        }
        // decode current (off the serial chain)
        const float c0 = __uint_as_float(dv.x << 16);
        const float c1 = __uint_as_float(dv.x & 0xffff0000u);
        const float c2 = __uint_as_float(dv.y << 16);
        const float c3 = __uint_as_float(dv.y & 0xffff0000u);
        const float ca = __uint_as_float(dab << 16);
        const float cb = __uint_as_float(dab & 0xffff0000u);
        const float E0 = __expf(c0), E1 = __expf(c1), E2 = __expf(c2), E3 = __expf(c3);
        const float Ea = __expf(ca), Eb = __expf(cb);
        // serial chain
        const float Mq = fmax_x2(fmax_x1(m));   // quad-local max (2 DPP)
        const float MqX = swz4(Mq);             // other quad's max (parallel)
        const float e = __expf(m - Mq);
        const float corr = __expf(MqX - Mq);    // cross-quad rescale
        const float p0l = add_x2(add_x1(e * E0));
        const float p1l = add_x2(add_x1(e * E1));
        const float p2l = add_x2(add_x1(e * E2));
        const float p3l = add_x2(add_x1(e * E3));
        const float p0 = fmaf(corr, swz4(p0l), p0l);
        const float p1 = fmaf(corr, swz4(p1l), p1l);
        const float p2 = fmaf(corr, swz4(p2l), p2l);
        const float p3 = fmaf(corr, swz4(p3l), p3l);
        const float Sb = fmaf(corr * gat_k(e), Ea, e * Eb);
        const float Slow = (j < 2) ? ((j == 0) ? p0 : p1)
                                   : ((j == 2) ? p2 : p3);
        const float S = (j < 4) ? Slow : Sb;
        m = Mq + __logf(S);
        dv = nv; dab = nab;
        sp = np;
    }
    gbuf[((long)(n * CHUNKS + c)) * 64 + l] = m;
}

// ---------------- butterfly lse helpers for kC ----------------
__device__ inline float lse8(float v) {
    const float m = max8(v);
    return m + __logf(sum8(__expf(v - m)));
}
__device__ inline float lse64(float v) {
    float m = v;
#pragma unroll
    for (int d = 1; d < 64; d <<= 1) m = fmaxf(m, __shfl_xor(m, d));
    float e = __expf(v - m);
#pragma unroll
    for (int d = 1; d < 64; d <<= 1) e += __shfl_xor(e, d);
    return m + __logf(e);
}

// ---------------- Kernel C: fold chunk matrices, emit logZ/T -------------
__global__ __launch_bounds__(64) void kC_combine(const float* __restrict__ gbuf,
                                                 float* __restrict__ logZT) {
    const int n = blockIdx.x;
    const int l = threadIdx.x;
    const int gi = (l & 7) * 8 + (l >> 3);
    float g[CHUNKS];
#pragma unroll
    for (int c = 0; c < CHUNKS; ++c)
        g[c] = gbuf[((long)(n * CHUNKS + c)) * 64 + gi];
    float u = -logf(8.f);
#pragma unroll
    for (int c = 0; c < CHUNKS; ++c) {
        const float nu = lse8(g[c] + u);
        u = __shfl(nu, ((l & 7) << 3) | (l >> 3));
    }
    const float z = lse64(u);
    if (l == 0) logZT[n] = z / (float)TT;
}

// ---------------- Kernel D: bf16 scores -> final f32 output --------------
__global__ __launch_bounds__(256) void kD_final(const ushort* __restrict__ sc,
                                                const float* __restrict__ logZT,
                                                float* __restrict__ out) {
    const long row = (long)blockIdx.x * 256 + threadIdx.x;
    const int n = (int)(row & (NN - 1));
    const float z = logZT[n];
    const ushort* srow = sc + row * SOUT;
    float st[48];
#pragma unroll
    for (int i = 0; i < 6; ++i) {
        const uint4 q = reinterpret_cast<const uint4*>(srow)[i];
        const unsigned wv[4] = {q.x, q.y, q.z, q.w};
#pragma unroll
        for (int t = 0; t < 4; ++t) {
            st[8 * i + 2 * t]     = __uint_as_float(wv[t] << 16);
            st[8 * i + 2 * t + 1] = __uint_as_float(wv[t] & 0xffff0000u);
        }
    }
    float a[48];
#pragma unroll
    for (int c = 0; c < 40; ++c) a[c] = st[sidx(c)] - z;
    const float y40 = st[40], y41 = st[41], y42 = st[42], y43 = st[43], y44 = st[44];
    const float m3 = fmaxf(fmaxf(y40, y41), y42);
    const float l3 = m3 + __logf(__expf(y40 - m3) + __expf(y41 - m3) + __expf(y42 - m3));
    a[40] = y40 - l3; a[41] = y41 - l3; a[42] = y42 - l3;
    const float mA = fmaxf(y40, y43);
    const float lA = mA + __logf(__expf(y40 - mA) + __expf(y43 - mA));
    a[43] = y40 - lA; a[44] = y43 - lA;
    a[45] = 0.f;
    const float mB = fmaxf(y40, y44);
    const float lB = mB + __logf(__expf(y40 - mB) + __expf(y44 - mB));
    a[46] = y40 - lB; a[47] = y44 - lB;
    float* orow = out + row * SOUT;
#pragma unroll
    for (int i = 0; i < 12; ++i)
        reinterpret_cast<float4*>(orow)[i] =
            make_float4(a[4 * i], a[4 * i + 1], a[4 * i + 2], a[4 * i + 3]);
}

extern "C" void kernel_launch(void* const* d_in, const int* in_sizes, int n_in,
                              void* d_out, int out_size, void* d_ws, size_t ws_size,
                              hipStream_t stream) {
    const float* x = (const float*)d_in[0];
    const float* W = (const float*)d_in[1];
    const float* b = (const float*)d_in[2];
    float* out = (float*)d_out;

    ushort* sc   = (ushort*)d_ws;                          // 512000*48 u16 = 49.15 MB
    float* gbuf  = (float*)((char*)d_ws + 49152000);       // 2.62 MB
    float* logZT = gbuf + (long)NN * CHUNKS * 64;          // 256 f32
    float* b48   = logZT + NN;                             // 48 f32
    ushort* Whi  = (ushort*)(b48 + SOUT);                  // 24 KB

    hipLaunchKernelGGL(kPrep, dim3(SOUT), dim3(DD), 0, stream, W, b, Whi, b48);
    hipLaunchKernelGGL(kA_mfma, dim3((TT * NN) / 64), dim3(256), 0, stream, x, Whi, b48, sc);
    hipLaunchKernelGGL(kB_scan, dim3(NN, CHUNKS), dim3(64), 0, stream, sc, gbuf);
    hipLaunchKernelGGL(kC_combine, dim3(NN), dim3(64), 0, stream, gbuf, logZT);
    hipLaunchKernelGGL(kD_final, dim3((TT * NN) / 256), dim3(256), 0, stream, sc, logZT, out);
}

// Round 7
// 240.761 us; speedup vs baseline: 2.0982x; 1.1052x over previous
//
#include <hip/hip_runtime.h>
#include <hip/hip_bf16.h>
#include <math.h>

#define TT 2000
#define NN 256
#define DD 256
#define SS 45
#define SOUT 48
#define NTRANS_C 40
#define CHUNKS 40
#define CLEN 50   // TT / CHUNKS

typedef __attribute__((ext_vector_type(8))) short bf16x8;
typedef __attribute__((ext_vector_type(4))) float f32x4;
typedef __attribute__((ext_vector_type(4))) int i32x4;

__device__ inline ushort f2bf_rne(float f) {
    unsigned u = __float_as_uint(f);
    unsigned r = u + 0x7fffu + ((u >> 16) & 1u);
    return (ushort)(r >> 16);
}
__device__ inline int pkbf(float lo, float hi) {
    return (int)((unsigned)f2bf_rne(lo) | ((unsigned)f2bf_rne(hi) << 16));
}
// score-buffer storage permutation (kB reads b64+b32):
//  c<32: -> 4*(c&7)+(c>>3) ; 32..35 -> 32+2k ; 36..39 -> 32+2k+1 ; c>=40 unchanged
__device__ __host__ __forceinline__ constexpr int sidx(int c) {
    return (c < 32) ? (4 * (c & 7) + (c >> 3))
         : (c < 36) ? (32 + 2 * (c - 32))
         : (c < 40) ? (32 + 2 * (c - 36) + 1)
         : c;
}
// LDS W swizzle: 16B slot index XORed with (row&7); idx in ushorts.
__device__ __forceinline__ int swz_idx(int s, int koff) {
    return s * DD + ((((koff >> 3) ^ (s & 7)) << 3) | (koff & 7));
}

// ---------------- Prep: W -> bf16 (RNE), pad to 48 rows; pad b ----------
__global__ __launch_bounds__(256) void kPrep(const float* __restrict__ W,
                                             const float* __restrict__ b,
                                             ushort* __restrict__ Whi,
                                             float* __restrict__ b48) {
    const int s = blockIdx.x;   // 0..47
    const int k = threadIdx.x;  // 0..255
    const float wv = (s < SS) ? W[s * DD + k] : 0.f;
    Whi[s * DD + k] = f2bf_rne(wv);
    if (k == 0) b48[s] = (s < SS) ? b[s] : 0.f;
}

// ---------------- Kernel A: bf16 MFMA GEMM + activations -----------------
// 8 waves/block, 64-VGPR cap -> 8 waves/SIMD. W staged once in swizzled LDS;
// K-loop has only the 2 streaming x-loads as VMEM.
__global__ __launch_bounds__(512, 8) void kA_mfma(const float* __restrict__ x,
                                                  const ushort* __restrict__ Whi,
                                                  const float* __restrict__ b48,
                                                  ushort* __restrict__ sc) {
    __shared__ ushort Wl[SOUT * DD];   // 24 KB, slot-swizzled
    const int tid = threadIdx.x;
    // stage W: uint4 = one 16B slot per thread-chunk
    for (int idx = tid; idx < SOUT * (DD / 8); idx += 512) {
        const int s = idx >> 5;            // row 0..47
        const int c8 = (idx & 31) * 8;     // col (ushorts), multiple of 8
        const uint4 v = *reinterpret_cast<const uint4*>(Whi + s * DD + c8);
        *reinterpret_cast<uint4*>(&Wl[swz_idx(s, c8)]) = v;
    }
    __syncthreads();

    const int l = tid & 63, w = tid >> 6;
    const long m0 = (long)blockIdx.x * 128 + w * 16;
    const int r16 = l & 15;   // A row / C col
    const int kg = l >> 4;    // k-group 0..3
    const float* xr = x + (m0 + r16) * DD + kg * 8;

    f32x4 acc[3] = {{0, 0, 0, 0}, {0, 0, 0, 0}, {0, 0, 0, 0}};

#pragma unroll
    for (int k0 = 0; k0 < DD; k0 += 32) {
        const float4 xa = *reinterpret_cast<const float4*>(xr + k0);
        const float4 xb = *reinterpret_cast<const float4*>(xr + k0 + 4);
        i32x4 av;
        av[0] = pkbf(xa.x, xa.y);
        av[1] = pkbf(xa.z, xa.w);
        av[2] = pkbf(xb.x, xb.y);
        av[3] = pkbf(xb.z, xb.w);
        const bf16x8 a = __builtin_bit_cast(bf16x8, av);
        const int koff = kg * 8 + k0;
        const bf16x8 b0 = *reinterpret_cast<const bf16x8*>(&Wl[swz_idx(0 * 16 + r16, koff)]);
        const bf16x8 b1 = *reinterpret_cast<const bf16x8*>(&Wl[swz_idx(1 * 16 + r16, koff)]);
        const bf16x8 b2 = *reinterpret_cast<const bf16x8*>(&Wl[swz_idx(2 * 16 + r16, koff)]);
        acc[0] = __builtin_amdgcn_mfma_f32_16x16x32_bf16(a, b0, acc[0], 0, 0, 0);
        acc[1] = __builtin_amdgcn_mfma_f32_16x16x32_bf16(a, b1, acc[1], 0, 0, 0);
        acc[2] = __builtin_amdgcn_mfma_f32_16x16x32_bf16(a, b2, acc[2], 0, 0, 0);
    }
    // epilogue: C layout col=lane&15, row=(lane>>4)*4+reg  [m89]
#pragma unroll
    for (int jt = 0; jt < 3; ++jt) {
        const int col = jt * 16 + r16;
        const float bias = b48[col];
        int si;
        if (jt < 2) si = 4 * (col & 7) + (col >> 3);
        else if (r16 < 8) si = (r16 < 4) ? (32 + 2 * r16) : (32 + 2 * (r16 - 4) + 1);
        else si = 40 + (r16 - 8);
#pragma unroll
        for (int r = 0; r < 4; ++r) {
            const long orow = m0 + kg * 4 + r;
            const float y = acc[jt][r] + bias;
            float v;
            if (col < NTRANS_C) {
                const float e = __expf(2.f * y);
                v = 5.f * (1.f - 2.f / (e + 1.f));   // 5*tanh(y)
            } else {
                v = y;
            }
            sc[orow * SOUT + si] = f2bf_rne(v);
        }
    }
}

// ---------------- DPP / swizzle cross-lane helpers -----------------------
#define DPP_XOR1 0xB1  // quad_perm(1,0,3,2)
#define DPP_XOR2 0x4E  // quad_perm(2,3,0,1)

__device__ inline float fmax_x1(float v) {
    const int d = __builtin_amdgcn_mov_dpp(__float_as_int(v), DPP_XOR1, 0xF, 0xF, true);
    return fmaxf(v, __int_as_float(d));
}
__device__ inline float fmax_x2(float v) {
    const int d = __builtin_amdgcn_mov_dpp(__float_as_int(v), DPP_XOR2, 0xF, 0xF, true);
    return fmaxf(v, __int_as_float(d));
}
__device__ inline float add_x1(float v) {
    const int d = __builtin_amdgcn_mov_dpp(__float_as_int(v), DPP_XOR1, 0xF, 0xF, true);
    return v + __int_as_float(d);
}
__device__ inline float add_x2(float v) {
    const int d = __builtin_amdgcn_mov_dpp(__float_as_int(v), DPP_XOR2, 0xF, 0xF, true);
    return v + __int_as_float(d);
}
__device__ inline float swz4(float v) {   // lane ^ 4
    return __int_as_float(__builtin_amdgcn_ds_swizzle(__float_as_int(v), 0x101F));
}
__device__ inline float fmax_x4(float v) { return fmaxf(v, swz4(v)); }
__device__ inline float add_x4(float v) { return v + swz4(v); }
__device__ inline float sum8(float v) { return add_x4(add_x2(add_x1(v))); }
__device__ inline float max8(float v) { return fmax_x4(fmax_x2(fmax_x1(v))); }
// lane' = (lane & ~7) | (lane & 3)  -> gather group-lane k
__device__ inline float gat_k(float v) {
    return __int_as_float(__builtin_amdgcn_ds_swizzle(__float_as_int(v), 0x001B));
}

// ---------------- Kernel B: per-(n,chunk) 8x8 log transfer matrix ----------
__global__ __launch_bounds__(64) void kB_scan(const ushort* __restrict__ sc,
                                              float* __restrict__ gbuf) {
    const int n = blockIdx.x;
    const int c = blockIdx.y;
    const int l = threadIdx.x;
    const int col = l >> 3;
    const int j = l & 7;
    const int k = j & 3;
    float m = (j == col) ? 0.f : -60.f;   // finite "-inf"
    const long stride = (long)NN * SOUT;  // in u16 elements
    const ushort* sp = sc + ((long)(c * CLEN) * NN + n) * SOUT;

    uint2 dv = *reinterpret_cast<const uint2*>(sp + 4 * j);
    unsigned dab = *reinterpret_cast<const unsigned*>(sp + 32 + 2 * k);

    for (int t = 0; t < CLEN; ++t) {
        const ushort* np = sp + stride;
        uint2 nv;
        unsigned nab;
        if (t + 1 < CLEN) {   // prefetch next step's scores
            nv = *reinterpret_cast<const uint2*>(np + 4 * j);
            nab = *reinterpret_cast<const unsigned*>(np + 32 + 2 * k);
        }
        const float c0 = __uint_as_float(dv.x << 16);
        const float c1 = __uint_as_float(dv.x & 0xffff0000u);
        const float c2 = __uint_as_float(dv.y << 16);
        const float c3 = __uint_as_float(dv.y & 0xffff0000u);
        const float ca = __uint_as_float(dab << 16);
        const float cb = __uint_as_float(dab & 0xffff0000u);
        const float E0 = __expf(c0), E1 = __expf(c1), E2 = __expf(c2), E3 = __expf(c3);
        const float Ea = __expf(ca), Eb = __expf(cb);
        const float Mq = fmax_x2(fmax_x1(m));   // quad-local max (2 DPP)
        const float MqX = swz4(Mq);             // other quad's max (parallel)
        const float e = __expf(m - Mq);
        const float corr = __expf(MqX - Mq);    // cross-quad rescale
        const float p0l = add_x2(add_x1(e * E0));
        const float p1l = add_x2(add_x1(e * E1));
        const float p2l = add_x2(add_x1(e * E2));
        const float p3l = add_x2(add_x1(e * E3));
        const float p0 = fmaf(corr, swz4(p0l), p0l);
        const float p1 = fmaf(corr, swz4(p1l), p1l);
        const float p2 = fmaf(corr, swz4(p2l), p2l);
        const float p3 = fmaf(corr, swz4(p3l), p3l);
        const float Sb = fmaf(corr * gat_k(e), Ea, e * Eb);
        const float Slow = (j < 2) ? ((j == 0) ? p0 : p1)
                                   : ((j == 2) ? p2 : p3);
        const float S = (j < 4) ? Slow : Sb;
        m = Mq + __logf(S);
        dv = nv; dab = nab;
        sp = np;
    }
    gbuf[((long)(n * CHUNKS + c)) * 64 + l] = m;
}

// ---------------- butterfly lse helpers for kC ----------------
__device__ inline float lse8(float v) {
    const float m = max8(v);
    return m + __logf(sum8(__expf(v - m)));
}
__device__ inline float lse64(float v) {
    float m = v;
#pragma unroll
    for (int d = 1; d < 64; d <<= 1) m = fmaxf(m, __shfl_xor(m, d));
    float e = __expf(v - m);
#pragma unroll
    for (int d = 1; d < 64; d <<= 1) e += __shfl_xor(e, d);
    return m + __logf(e);
}

// ---------------- Kernel C: fold chunk matrices, emit logZ/T -------------
__global__ __launch_bounds__(64) void kC_combine(const float* __restrict__ gbuf,
                                                 float* __restrict__ logZT) {
    const int n = blockIdx.x;
    const int l = threadIdx.x;
    const int gi = (l & 7) * 8 + (l >> 3);
    float g[CHUNKS];
#pragma unroll
    for (int c = 0; c < CHUNKS; ++c)
        g[c] = gbuf[((long)(n * CHUNKS + c)) * 64 + gi];
    float u = -logf(8.f);
#pragma unroll
    for (int c = 0; c < CHUNKS; ++c) {
        const float nu = lse8(g[c] + u);
        u = __shfl(nu, ((l & 7) << 3) | (l >> 3));
    }
    const float z = lse64(u);
    if (l == 0) logZT[n] = z / (float)TT;
}

// ---------------- Kernel D: bf16 scores -> final f32 output --------------
__global__ __launch_bounds__(256) void kD_final(const ushort* __restrict__ sc,
                                                const float* __restrict__ logZT,
                                                float* __restrict__ out) {
    const long row = (long)blockIdx.x * 256 + threadIdx.x;
    const int n = (int)(row & (NN - 1));
    const float z = logZT[n];
    const ushort* srow = sc + row * SOUT;
    float st[48];
#pragma unroll
    for (int i = 0; i < 6; ++i) {
        const uint4 q = reinterpret_cast<const uint4*>(srow)[i];
        const unsigned wv[4] = {q.x, q.y, q.z, q.w};
#pragma unroll
        for (int t = 0; t < 4; ++t) {
            st[8 * i + 2 * t]     = __uint_as_float(wv[t] << 16);
            st[8 * i + 2 * t + 1] = __uint_as_float(wv[t] & 0xffff0000u);
        }
    }
    float a[48];
#pragma unroll
    for (int c = 0; c < 40; ++c) a[c] = st[sidx(c)] - z;
    const float y40 = st[40], y41 = st[41], y42 = st[42], y43 = st[43], y44 = st[44];
    const float m3 = fmaxf(fmaxf(y40, y41), y42);
    const float l3 = m3 + __logf(__expf(y40 - m3) + __expf(y41 - m3) + __expf(y42 - m3));
    a[40] = y40 - l3; a[41] = y41 - l3; a[42] = y42 - l3;
    const float mA = fmaxf(y40, y43);
    const float lA = mA + __logf(__expf(y40 - mA) + __expf(y43 - mA));
    a[43] = y40 - lA; a[44] = y43 - lA;
    a[45] = 0.f;
    const float mB = fmaxf(y40, y44);
    const float lB = mB + __logf(__expf(y40 - mB) + __expf(y44 - mB));
    a[46] = y40 - lB; a[47] = y44 - lB;
    float* orow = out + row * SOUT;
#pragma unroll
    for (int i = 0; i < 12; ++i)
        reinterpret_cast<float4*>(orow)[i] =
            make_float4(a[4 * i], a[4 * i + 1], a[4 * i + 2], a[4 * i + 3]);
}

extern "C" void kernel_launch(void* const* d_in, const int* in_sizes, int n_in,
                              void* d_out, int out_size, void* d_ws, size_t ws_size,
                              hipStream_t stream) {
    const float* x = (const float*)d_in[0];
    const float* W = (const float*)d_in[1];
    const float* b = (const float*)d_in[2];
    float* out = (float*)d_out;

    ushort* sc   = (ushort*)d_ws;                          // 512000*48 u16 = 49.15 MB
    float* gbuf  = (float*)((char*)d_ws + 49152000);       // 2.62 MB
    float* logZT = gbuf + (long)NN * CHUNKS * 64;          // 256 f32
    float* b48   = logZT + NN;                             // 48 f32
    ushort* Whi  = (ushort*)(b48 + SOUT);                  // 24 KB

    hipLaunchKernelGGL(kPrep, dim3(SOUT), dim3(DD), 0, stream, W, b, Whi, b48);
    hipLaunchKernelGGL(kA_mfma, dim3((TT * NN) / 128), dim3(512), 0, stream, x, Whi, b48, sc);
    hipLaunchKernelGGL(kB_scan, dim3(NN, CHUNKS), dim3(64), 0, stream, sc, gbuf);
    hipLaunchKernelGGL(kC_combine, dim3(NN), dim3(64), 0, stream, gbuf, logZT);
    hipLaunchKernelGGL(kD_final, dim3((TT * NN) / 256), dim3(256), 0, stream, sc, logZT, out);
}